// Round 1
// baseline (5035.828 us; speedup 1.0000x reference)
//
#include <hip/hip_runtime.h>
#include <hip/hip_cooperative_groups.h>
#include <math.h>

namespace cg = cooperative_groups;

#define B_N 128      // batch
#define NN 256       // n == m
#define DD 128       // feature dim
#define MAX_ITER 200
#define TOL 0.005f
#define BVAL (1.0f/256.0f)

__device__ __forceinline__ float wave_reduce_sum(float v) {
  #pragma unroll
  for (int off = 32; off >= 1; off >>= 1) v += __shfl_xor(v, off);
  return v;
}

// ---------------- K1: per-(b,d) normalization constant c = mean/sqrt(var+1e-4),
// plus zero-init of crit slots, dmax, and the dis accumulators in d_out. ----------------
__global__ __launch_bounds__(256) void prep_kernel(
    const float* __restrict__ X, const float* __restrict__ Y,
    float* __restrict__ cx, float* __restrict__ cy,
    int* __restrict__ dmax_i, float* __restrict__ crit_slots,
    float* __restrict__ out) {
  int gid = blockIdx.x * 256 + threadIdx.x;          // 0..32767
  if (gid < 16) crit_slots[gid] = 0.0f;
  if (gid < B_N) { dmax_i[gid] = (int)0xFF800000; out[gid] = 0.0f; }  // -inf bits
  const float* src = (gid < 16384) ? X : Y;
  float* dst       = (gid < 16384) ? cx : cy;
  int g = gid & 16383;
  int b = g >> 7, d = g & 127;
  const float* p = src + ((size_t)b << 15) + d;      // b*256*128 + d
  float s = 0.f, ss = 0.f;
  #pragma unroll 8
  for (int i = 0; i < NN; i++) { float x = p[(size_t)i * DD]; s += x; ss = fmaf(x, x, ss); }
  float mean = s * (1.0f/256.0f);
  float var  = (ss - 256.0f * mean * mean) * (1.0f/255.0f);   // ddof=1
  dst[g] = mean / sqrtf(var + 1e-4f);
}

// ---------------- K2: dist[b][i][j] = sum_d (Xn - Yn)^2, tiled 64x64, + per-batch max ----------------
__global__ __launch_bounds__(256) void dist_kernel(
    const float* __restrict__ X, const float* __restrict__ Y,
    const float* __restrict__ cx, const float* __restrict__ cy,
    float* __restrict__ dist, int* __restrict__ dmax_i) {
  int b  = blockIdx.x;
  int i0 = blockIdx.y * 64, j0 = blockIdx.z * 64;
  __shared__ float xs[64][65], ys[64][65];
  __shared__ int bm;
  const float* Xb  = X + (size_t)b * (NN*DD);
  const float* Yb  = Y + (size_t)b * (NN*DD);
  const float* cxb = cx + b * DD;
  const float* cyb = cy + b * DD;
  if (threadIdx.x == 0) bm = (int)0xFF800000;
  float acc[4][4] = {};
  for (int dblk = 0; dblk < DD; dblk += 64) {
    for (int t = threadIdx.x; t < 1024; t += 256) {   // 64 rows x 16 float4
      int r = t >> 4, q = t & 15;
      float4 xv = ((const float4*)(Xb + (size_t)(i0 + r) * DD + dblk))[q];
      float4 cv = ((const float4*)(cxb + dblk))[q];
      xs[r][4*q+0] = xv.x - cv.x; xs[r][4*q+1] = xv.y - cv.y;
      xs[r][4*q+2] = xv.z - cv.z; xs[r][4*q+3] = xv.w - cv.w;
      float4 yv = ((const float4*)(Yb + (size_t)(j0 + r) * DD + dblk))[q];
      float4 dv = ((const float4*)(cyb + dblk))[q];
      ys[r][4*q+0] = yv.x - dv.x; ys[r][4*q+1] = yv.y - dv.y;
      ys[r][4*q+2] = yv.z - dv.z; ys[r][4*q+3] = yv.w - dv.w;
    }
    __syncthreads();
    int ti = threadIdx.x >> 4, tj = threadIdx.x & 15;
    #pragma unroll 4
    for (int d = 0; d < 64; d++) {
      float xr[4], yc[4];
      #pragma unroll
      for (int r = 0; r < 4; r++) xr[r] = xs[ti*4+r][d];
      #pragma unroll
      for (int c = 0; c < 4; c++) yc[c] = ys[tj*4+c][d];
      #pragma unroll
      for (int r = 0; r < 4; r++)
        #pragma unroll
        for (int c = 0; c < 4; c++) { float df = xr[r] - yc[c]; acc[r][c] = fmaf(df, df, acc[r][c]); }
    }
    __syncthreads();
  }
  int ti = threadIdx.x >> 4, tj = threadIdx.x & 15;
  float mx = -INFINITY;
  #pragma unroll
  for (int r = 0; r < 4; r++) {
    float4 o = make_float4(acc[r][0], acc[r][1], acc[r][2], acc[r][3]);
    ((float4*)(dist + ((size_t)b*NN + i0 + ti*4 + r) * NN + j0))[tj] = o;
    mx = fmaxf(mx, fmaxf(fmaxf(o.x, o.y), fmaxf(o.z, o.w)));
  }
  atomicMax(&bm, __float_as_int(mx));   // dist >= 0 (minus rounding); max is large positive
  __syncthreads();
  if (threadIdx.x == 0) atomicMax(dmax_i + b, bm);
}

// ---------------- K3: k = p * exp((s - dist/dmax)*100), elementwise ----------------
__global__ __launch_bounds__(256) void kbuild_kernel(
    const float* __restrict__ dist, const int* __restrict__ dmax_i, float* __restrict__ kmat) {
  size_t id = (size_t)blockIdx.x * 256 + threadIdx.x;   // over 128*256*256
  int b = (int)(id >> 16);
  int rem = (int)(id & 65535);
  int i = rem >> 8, j = rem & 255;
  float inv = 1.0f / __int_as_float(dmax_i[b]);
  float d  = dist[id] * inv;
  float df = (float)(i - j);
  float p  = expf(df * df * (-1.0f/400.0f)) * 0.03989422804014327f; // 1/(10*sqrt(2*pi))
  float tt = df * (1.0f/256.0f);
  float s  = 0.1f / (tt * tt + 1.0f);
  kmat[id] = p * expf((s - d) * 100.0f);
}

// ---------------- K4: cooperative Sinkhorn with global convergence ----------------
// matvecT: out[j=tid] = sum_i K[i][j]*u[i]  (column-parallel; coalesced row sweeps)
__device__ __forceinline__ float matvecT(const float* __restrict__ Kb, const float* __restrict__ uin, int tid) {
  float a0=0.f, a1=0.f, a2=0.f, a3=0.f;
  const float* Kc = Kb + tid;
  #pragma unroll 4
  for (int i = 0; i < NN; i += 4) {
    float b0 = uin[i], b1 = uin[i+1], b2 = uin[i+2], b3 = uin[i+3];
    a0 = fmaf(Kc[(i+0)*NN], b0, a0);
    a1 = fmaf(Kc[(i+1)*NN], b1, a1);
    a2 = fmaf(Kc[(i+2)*NN], b2, a2);
    a3 = fmaf(Kc[(i+3)*NN], b3, a3);
  }
  return (a0 + a1) + (a2 + a3);
}

// matvecN: out[i] = sum_j K[i][j]*w[j]; wave handles 64 rows, lanes split j, butterfly reduce
__device__ __forceinline__ void matvecN(const float* __restrict__ Kb, const float* __restrict__ win,
                                        float* __restrict__ outv, int lane, int wave) {
  float w0 = win[lane], w1 = win[lane+64], w2 = win[lane+128], w3 = win[lane+192];
  const float* Kr0 = Kb + (size_t)(wave * 64) * NN + lane;
  #pragma unroll 2
  for (int r = 0; r < 64; r++) {
    const float* Kr = Kr0 + r * NN;
    float s2 = Kr[0] * w0;
    s2 = fmaf(Kr[64],  w1, s2);
    s2 = fmaf(Kr[128], w2, s2);
    s2 = fmaf(Kr[192], w3, s2);
    s2 = wave_reduce_sum(s2);
    if (lane == 0) outv[wave * 64 + r] = s2;
  }
}

__global__ __launch_bounds__(256) void sinkhorn_kernel(
    const float* __restrict__ kmat, float* __restrict__ u_g,
    float* __restrict__ v_g, float* __restrict__ crit_slots) {
  cg::grid_group grid = cg::this_grid();
  int tid = threadIdx.x, lane = tid & 63, wave = tid >> 6;
  int b = blockIdx.x;
  const float* Kb = kmat + (size_t)b * (NN*NN);
  __shared__ float us[NN], wsh[NN], t1[NN];
  __shared__ float red[4];
  us[tid] = 1.0f / 256.0f;       // u0 = 1/n
  float v_reg = 0.0f;            // v0 = 0
  __syncthreads();
  int compt = 0, check_idx = 0;
  bool done = false;
  while (!done && compt < MAX_ITER) {
    // u1 = 1/(n*K@(b/(K^T@u)))
    float tT = matvecT(Kb, us, tid);
    wsh[tid] = BVAL / tT;
    __syncthreads();
    matvecN(Kb, wsh, t1, lane, wave);
    __syncthreads();
    float u1 = 1.0f / (256.0f * t1[tid]);
    int c1 = compt + 1;
    bool pred = ((c1 % 20) == 1) || (c1 == MAX_ITER);
    us[tid] = u1;                 // safe: old us readers finished before prior barrier
    __syncthreads();
    if (!pred) { compt = c1; continue; }
    // convergence-check branch: v2 = b/(K^T u1); u2 = 1/(n K v2); crit = sum|v2*(K^T u2)-b|
    float tT2 = matvecT(Kb, us, tid);
    float v2 = BVAL / tT2;
    wsh[tid] = v2;
    __syncthreads();
    matvecN(Kb, wsh, t1, lane, wave);
    __syncthreads();
    float u2 = 1.0f / (256.0f * t1[tid]);
    us[tid] = u2;
    __syncthreads();
    float tT3 = matvecT(Kb, us, tid);
    float cpart = fabsf(v2 * tT3 - BVAL);
    float csum = wave_reduce_sum(cpart);
    if (lane == 0) red[wave] = csum;
    __syncthreads();
    if (tid == 0) atomicAdd(&crit_slots[check_idx], red[0] + red[1] + red[2] + red[3]);
    grid.sync();
    if (tid == 0)
      red[0] = __hip_atomic_load(&crit_slots[check_idx], __ATOMIC_RELAXED, __HIP_MEMORY_SCOPE_AGENT);
    __syncthreads();
    float crit = red[0];
    check_idx++;
    bool conv = (crit < TOL) || isnan(crit);
    v_reg = v2;
    if (conv) { done = true; compt = c1; }
    else      { compt = c1 + 1; }
  }
  u_g[b * NN + tid] = us[tid];
  v_g[b * NN + tid] = v_reg;
}

// ---------------- K5: dis[b] = sum_ij u*k*(dist/dmax)*v ; t = v^T * (u*k) ----------------
__global__ __launch_bounds__(256) void out_kernel(
    const float* __restrict__ kmat, const float* __restrict__ dist,
    const int* __restrict__ dmax_i, const float* __restrict__ u_g,
    const float* __restrict__ v_g, float* __restrict__ out) {
  int b = blockIdx.x;
  int tid = threadIdx.x, lane = tid & 63, wave = tid >> 6;
  __shared__ float vs[NN];
  __shared__ float usr[16];
  __shared__ float red[4];
  vs[tid] = v_g[b * NN + tid];
  if (tid < 16) usr[tid] = u_g[b * NN + blockIdx.y * 16 + tid];
  __syncthreads();
  float inv = 1.0f / __int_as_float(dmax_i[b]);
  float vj = vs[tid];
  const float* kb = kmat + (size_t)b * (NN*NN);
  const float* db = dist + (size_t)b * (NN*NN);
  float* tout = out + B_N + (size_t)b * (NN*NN);
  float dpart = 0.f;
  #pragma unroll 4
  for (int r = 0; r < 16; r++) {
    int i = blockIdx.y * 16 + r;
    float kv = kb[i * NN + tid];
    float ui = usr[r];
    float tv = (ui * kv) * vj;                 // v^T * (u*k)
    tout[i * NN + tid] = tv;
    dpart = fmaf(tv, db[i * NN + tid] * inv, dpart);   // u*k*d*v
  }
  dpart = wave_reduce_sum(dpart);
  if (lane == 0) red[wave] = dpart;
  __syncthreads();
  if (tid == 0) atomicAdd(out + b, red[0] + red[1] + red[2] + red[3]);
}

// ---------------- launch ----------------
extern "C" void kernel_launch(void* const* d_in, const int* in_sizes, int n_in,
                              void* d_out, int out_size, void* d_ws, size_t ws_size,
                              hipStream_t stream) {
  const float* X = (const float*)d_in[0];
  const float* Y = (const float*)d_in[1];
  float* out = (float*)d_out;
  char* ws = (char*)d_ws;
  // ws layout (bytes): dist 32MB | k 32MB | cx 64KB | cy 64KB | u 128KB | v 128KB | dmax 512B | crit 64B
  float* dist  = (float*)(ws);
  float* kmat  = (float*)(ws + 33554432);
  float* cx    = (float*)(ws + 67108864);
  float* cy    = (float*)(ws + 67174400);
  float* u_g   = (float*)(ws + 67239936);
  float* v_g   = (float*)(ws + 67371008);
  int*   dmax  = (int*)  (ws + 67502080);
  float* crit  = (float*)(ws + 67502592);

  hipLaunchKernelGGL(prep_kernel, dim3(128), dim3(256), 0, stream, X, Y, cx, cy, dmax, crit, out);
  hipLaunchKernelGGL(dist_kernel, dim3(128, 4, 4), dim3(256), 0, stream, X, Y, cx, cy, dist, dmax);
  hipLaunchKernelGGL(kbuild_kernel, dim3(32768), dim3(256), 0, stream, dist, dmax, kmat);

  void* args[] = { (void*)&kmat, (void*)&u_g, (void*)&v_g, (void*)&crit };
  hipLaunchCooperativeKernel((void*)sinkhorn_kernel, dim3(128), dim3(256), args, 0, stream);

  hipLaunchKernelGGL(out_kernel, dim3(128, 16), dim3(256), 0, stream, kmat, dist, dmax, u_g, v_g, out);
}

// Round 3
// 2033.695 us; speedup vs baseline: 2.4762x; 2.4762x over previous
//
#include <hip/hip_runtime.h>
#include <hip/hip_cooperative_groups.h>
#include <math.h>

namespace cg = cooperative_groups;

#define B_N 128      // batch
#define NN 256       // n == m
#define DD 128       // feature dim
#define MAX_ITER 200
#define TOL 0.005f
#define BVAL (1.0f/256.0f)

__device__ __forceinline__ float wave_reduce_sum(float v) {
  #pragma unroll
  for (int off = 32; off >= 1; off >>= 1) v += __shfl_xor(v, off);
  return v;
}

// ---------------- K1: per-(b,d) normalization constant c = mean/sqrt(var+1e-4),
// plus zero-init of crit slots, dmax, and the dis accumulators in d_out. ----------------
__global__ __launch_bounds__(256) void prep_kernel(
    const float* __restrict__ X, const float* __restrict__ Y,
    float* __restrict__ cx, float* __restrict__ cy,
    int* __restrict__ dmax_i, float* __restrict__ crit_slots,
    float* __restrict__ out) {
  int gid = blockIdx.x * 256 + threadIdx.x;          // 0..32767
  if (gid < 16) crit_slots[gid] = 0.0f;
  if (gid < B_N) { dmax_i[gid] = (int)0xFF800000; out[gid] = 0.0f; }  // -inf bits
  const float* src = (gid < 16384) ? X : Y;
  float* dst       = (gid < 16384) ? cx : cy;
  int g = gid & 16383;
  int b = g >> 7, d = g & 127;
  const float* p = src + ((size_t)b << 15) + d;      // b*256*128 + d
  float s = 0.f, ss = 0.f;
  #pragma unroll 8
  for (int i = 0; i < NN; i++) { float x = p[(size_t)i * DD]; s += x; ss = fmaf(x, x, ss); }
  float mean = s * (1.0f/256.0f);
  float var  = (ss - 256.0f * mean * mean) * (1.0f/255.0f);   // ddof=1
  dst[g] = mean / sqrtf(var + 1e-4f);
}

// ---------------- K2: dist[b][i][j] = sum_d (Xn - Yn)^2, tiled 64x64, + per-batch max ----------------
__global__ __launch_bounds__(256) void dist_kernel(
    const float* __restrict__ X, const float* __restrict__ Y,
    const float* __restrict__ cx, const float* __restrict__ cy,
    float* __restrict__ dist, int* __restrict__ dmax_i) {
  int b  = blockIdx.x;
  int i0 = blockIdx.y * 64, j0 = blockIdx.z * 64;
  __shared__ float xs[64][65], ys[64][65];
  __shared__ int bm;
  const float* Xb  = X + (size_t)b * (NN*DD);
  const float* Yb  = Y + (size_t)b * (NN*DD);
  const float* cxb = cx + b * DD;
  const float* cyb = cy + b * DD;
  if (threadIdx.x == 0) bm = (int)0xFF800000;
  float acc[4][4] = {};
  for (int dblk = 0; dblk < DD; dblk += 64) {
    for (int t = threadIdx.x; t < 1024; t += 256) {   // 64 rows x 16 float4
      int r = t >> 4, q = t & 15;
      float4 xv = ((const float4*)(Xb + (size_t)(i0 + r) * DD + dblk))[q];
      float4 cv = ((const float4*)(cxb + dblk))[q];
      xs[r][4*q+0] = xv.x - cv.x; xs[r][4*q+1] = xv.y - cv.y;
      xs[r][4*q+2] = xv.z - cv.z; xs[r][4*q+3] = xv.w - cv.w;
      float4 yv = ((const float4*)(Yb + (size_t)(j0 + r) * DD + dblk))[q];
      float4 dv = ((const float4*)(cyb + dblk))[q];
      ys[r][4*q+0] = yv.x - dv.x; ys[r][4*q+1] = yv.y - dv.y;
      ys[r][4*q+2] = yv.z - dv.z; ys[r][4*q+3] = yv.w - dv.w;
    }
    __syncthreads();
    int ti = threadIdx.x >> 4, tj = threadIdx.x & 15;
    #pragma unroll 4
    for (int d = 0; d < 64; d++) {
      float xr[4], yc[4];
      #pragma unroll
      for (int r = 0; r < 4; r++) xr[r] = xs[ti*4+r][d];
      #pragma unroll
      for (int c = 0; c < 4; c++) yc[c] = ys[tj*4+c][d];
      #pragma unroll
      for (int r = 0; r < 4; r++)
        #pragma unroll
        for (int c = 0; c < 4; c++) { float df = xr[r] - yc[c]; acc[r][c] = fmaf(df, df, acc[r][c]); }
    }
    __syncthreads();
  }
  int ti = threadIdx.x >> 4, tj = threadIdx.x & 15;
  float mx = -INFINITY;
  #pragma unroll
  for (int r = 0; r < 4; r++) {
    float4 o = make_float4(acc[r][0], acc[r][1], acc[r][2], acc[r][3]);
    ((float4*)(dist + ((size_t)b*NN + i0 + ti*4 + r) * NN + j0))[tj] = o;
    mx = fmaxf(mx, fmaxf(fmaxf(o.x, o.y), fmaxf(o.z, o.w)));
  }
  atomicMax(&bm, __float_as_int(mx));   // dist >= 0; max is large positive
  __syncthreads();
  if (threadIdx.x == 0) atomicMax(dmax_i + b, bm);
}

// ---------------- K3: k = p * exp((s - dist/dmax)*100), elementwise ----------------
__global__ __launch_bounds__(256) void kbuild_kernel(
    const float* __restrict__ dist, const int* __restrict__ dmax_i, float* __restrict__ kmat) {
  size_t id = (size_t)blockIdx.x * 256 + threadIdx.x;   // over 128*256*256
  int b = (int)(id >> 16);
  int rem = (int)(id & 65535);
  int i = rem >> 8, j = rem & 255;
  float inv = 1.0f / __int_as_float(dmax_i[b]);
  float d  = dist[id] * inv;
  float df = (float)(i - j);
  float p  = expf(df * df * (-1.0f/400.0f)) * 0.03989422804014327f; // 1/(10*sqrt(2*pi))
  float tt = df * (1.0f/256.0f);
  float s  = 0.1f / (tt * tt + 1.0f);
  kmat[id] = p * expf((s - d) * 100.0f);
}

// ---------------- K4: cooperative Sinkhorn, K register-resident ----------------
// Layout: 16 waves; wave w owns rows [16w,16w+16). lane bits:
// lc = lane&15 (column group, 16 cols), lr = lane>>4 (row group, 4 rows).
// Lane register tile: Kreg[r][q] = K[16w+4lr+r][16lc+4q .. +4)  (4x16 floats).

__device__ __forceinline__ void mvT_accum(const float4 (&K)[4][4],
                                          const float* __restrict__ usrc,
                                          int row0, int w, int lc, int lr,
                                          float pt[][NN]) {
  // q[c] = sum over this lane's 4 rows of K[r][c]*u[row0+r]; then reduce over lr.
  float4 uv = *(const float4*)(usrc + row0);
  float ur[4] = {uv.x, uv.y, uv.z, uv.w};
  float q[16];
  #pragma unroll
  for (int c = 0; c < 16; c++) q[c] = 0.f;
  #pragma unroll
  for (int c4 = 0; c4 < 4; c4++) {
    #pragma unroll
    for (int r = 0; r < 4; r++) {
      q[4*c4+0] = fmaf(K[r][c4].x, ur[r], q[4*c4+0]);
      q[4*c4+1] = fmaf(K[r][c4].y, ur[r], q[4*c4+1]);
      q[4*c4+2] = fmaf(K[r][c4].z, ur[r], q[4*c4+2]);
      q[4*c4+3] = fmaf(K[r][c4].w, ur[r], q[4*c4+3]);
    }
  }
  #pragma unroll
  for (int c = 0; c < 16; c++) {
    q[c] += __shfl_xor(q[c], 16);
    q[c] += __shfl_xor(q[c], 32);
  }
  if (lr == 0) {
    float4* dst = (float4*)&pt[w][lc * 16];
    dst[0] = make_float4(q[0],  q[1],  q[2],  q[3]);
    dst[1] = make_float4(q[4],  q[5],  q[6],  q[7]);
    dst[2] = make_float4(q[8],  q[9],  q[10], q[11]);
    dst[3] = make_float4(q[12], q[13], q[14], q[15]);
  }
}

__device__ __forceinline__ void mvN_run(const float4 (&K)[4][4],
                                        const float* __restrict__ wsrc,
                                        int col0, int row0, int lc,
                                        float* __restrict__ udst) {
  // p[r] = sum over this lane's 16 cols of K[r][c]*w[col0+c]; reduce over lc; u = 1/(256*p).
  const float4* wv4 = (const float4*)(wsrc + col0);
  float4 w0 = wv4[0], w1 = wv4[1], w2 = wv4[2], w3 = wv4[3];
  float p[4];
  #pragma unroll
  for (int r = 0; r < 4; r++) {
    float a = K[r][0].x * w0.x;
    a = fmaf(K[r][0].y, w0.y, a); a = fmaf(K[r][0].z, w0.z, a); a = fmaf(K[r][0].w, w0.w, a);
    float bq = K[r][1].x * w1.x;
    bq = fmaf(K[r][1].y, w1.y, bq); bq = fmaf(K[r][1].z, w1.z, bq); bq = fmaf(K[r][1].w, w1.w, bq);
    a = fmaf(K[r][2].x, w2.x, a);
    a = fmaf(K[r][2].y, w2.y, a); a = fmaf(K[r][2].z, w2.z, a); a = fmaf(K[r][2].w, w2.w, a);
    bq = fmaf(K[r][3].x, w3.x, bq);
    bq = fmaf(K[r][3].y, w3.y, bq); bq = fmaf(K[r][3].z, w3.z, bq); bq = fmaf(K[r][3].w, w3.w, bq);
    p[r] = a + bq;
  }
  #pragma unroll
  for (int r = 0; r < 4; r++) {
    p[r] += __shfl_xor(p[r], 1);
    p[r] += __shfl_xor(p[r], 2);
    p[r] += __shfl_xor(p[r], 4);
    p[r] += __shfl_xor(p[r], 8);
  }
  if (lc == 0) {
    *(float4*)(udst + row0) = make_float4(1.0f/(256.0f*p[0]), 1.0f/(256.0f*p[1]),
                                          1.0f/(256.0f*p[2]), 1.0f/(256.0f*p[3]));
  }
}

#define STAGE1() do { int j_ = tid & 255, g_ = tid >> 8; \
  pt2[g_][j_] = ((pt[4*g_+0][j_] + pt[4*g_+1][j_]) + (pt[4*g_+2][j_] + pt[4*g_+3][j_])); } while(0)

__global__ __launch_bounds__(1024, 4) void sinkhorn_kernel(
    const float* __restrict__ kmat, float* __restrict__ u_g,
    float* __restrict__ v_g, float* __restrict__ crit_slots) {
  cg::grid_group grid = cg::this_grid();
  const int tid = threadIdx.x;
  const int w = tid >> 6, lane = tid & 63;
  const int lc = lane & 15, lr = lane >> 4;
  const int b = blockIdx.x;
  const int row0 = 16*w + 4*lr;
  const int col0 = 16*lc;
  const float* Kb = kmat + (size_t)b * (NN*NN);
  __shared__ __align__(16) float us[NN], wsh[NN];
  __shared__ __align__(16) float pt[16][NN];
  __shared__ __align__(16) float pt2[4][NN];
  __shared__ float red[20];

  float4 Kreg[4][4];
  #pragma unroll
  for (int r = 0; r < 4; r++) {
    const float4* src = (const float4*)(Kb + (size_t)(row0 + r) * NN + col0);
    #pragma unroll
    for (int q = 0; q < 4; q++) Kreg[r][q] = src[q];
  }
  if (tid < NN) us[tid] = BVAL;     // u0 = 1/n
  __syncthreads();

  int compt = 0, check_idx = 0;
  bool done = false;
  while (!done && compt < MAX_ITER) {
    // ---- u1 = 1/(n * K @ (b / (K^T @ u))) ----
    mvT_accum(Kreg, us, row0, w, lc, lr, pt);
    __syncthreads();
    STAGE1();
    __syncthreads();
    if (tid < NN) wsh[tid] = BVAL / ((pt2[0][tid]+pt2[1][tid]) + (pt2[2][tid]+pt2[3][tid]));
    __syncthreads();
    mvN_run(Kreg, wsh, col0, row0, lc, us);
    __syncthreads();
    int c1 = compt + 1;
    bool pred = ((c1 % 20) == 1) || (c1 == MAX_ITER);
    if (!pred) { compt = c1; continue; }
    // ---- convergence branch: v2 = b/(K^T u1) ----
    mvT_accum(Kreg, us, row0, w, lc, lr, pt);
    __syncthreads();
    STAGE1();
    __syncthreads();
    if (tid < NN) wsh[tid] = BVAL / ((pt2[0][tid]+pt2[1][tid]) + (pt2[2][tid]+pt2[3][tid]));  // v2
    __syncthreads();
    // ---- u2 = 1/(n K v2) ----
    mvN_run(Kreg, wsh, col0, row0, lc, us);
    __syncthreads();
    // ---- crit = sum |v2 * (K^T u2) - b| ----
    mvT_accum(Kreg, us, row0, w, lc, lr, pt);
    __syncthreads();
    STAGE1();
    __syncthreads();
    float cp = 0.f;
    if (tid < NN) {
      float tT3 = (pt2[0][tid]+pt2[1][tid]) + (pt2[2][tid]+pt2[3][tid]);
      cp = fabsf(wsh[tid] * tT3 - BVAL);
    }
    cp = wave_reduce_sum(cp);
    if (lane == 0) red[w] = cp;
    __syncthreads();
    if (tid == 0) atomicAdd(&crit_slots[check_idx], red[0]+red[1]+red[2]+red[3]);
    grid.sync();
    if (tid == 0)
      red[16] = __hip_atomic_load(&crit_slots[check_idx], __ATOMIC_RELAXED, __HIP_MEMORY_SCOPE_AGENT);
    __syncthreads();
    float crit = red[16];
    check_idx++;
    bool conv = (crit < TOL) || isnan(crit);
    if (conv) { done = true; compt = c1; }
    else      { compt = c1 + 1; }
  }
  if (tid < NN) {
    u_g[b*NN + tid] = us[tid];
    v_g[b*NN + tid] = wsh[tid];     // v only ever set at checks; loop always exits on a check
  }
}

// ---------------- K5: dis[b] = sum_ij u*k*(dist/dmax)*v ; t = v^T * (u*k) ----------------
__global__ __launch_bounds__(256) void out_kernel(
    const float* __restrict__ kmat, const float* __restrict__ dist,
    const int* __restrict__ dmax_i, const float* __restrict__ u_g,
    const float* __restrict__ v_g, float* __restrict__ out) {
  int b = blockIdx.x;
  int tid = threadIdx.x, lane = tid & 63, wave = tid >> 6;
  __shared__ float vs[NN];
  __shared__ float usr[16];
  __shared__ float red[4];
  vs[tid] = v_g[b * NN + tid];
  if (tid < 16) usr[tid] = u_g[b * NN + blockIdx.y * 16 + tid];
  __syncthreads();
  float inv = 1.0f / __int_as_float(dmax_i[b]);
  float vj = vs[tid];
  const float* kb = kmat + (size_t)b * (NN*NN);
  const float* db = dist + (size_t)b * (NN*NN);
  float* tout = out + B_N + (size_t)b * (NN*NN);
  float dpart = 0.f;
  #pragma unroll 4
  for (int r = 0; r < 16; r++) {
    int i = blockIdx.y * 16 + r;
    float kv = kb[i * NN + tid];
    float ui = usr[r];
    float tv = (ui * kv) * vj;                 // v^T * (u*k)
    tout[i * NN + tid] = tv;
    dpart = fmaf(tv, db[i * NN + tid] * inv, dpart);   // u*k*d*v
  }
  dpart = wave_reduce_sum(dpart);
  if (lane == 0) red[wave] = dpart;
  __syncthreads();
  if (tid == 0) atomicAdd(out + b, red[0] + red[1] + red[2] + red[3]);
}

// ---------------- launch ----------------
extern "C" void kernel_launch(void* const* d_in, const int* in_sizes, int n_in,
                              void* d_out, int out_size, void* d_ws, size_t ws_size,
                              hipStream_t stream) {
  const float* X = (const float*)d_in[0];
  const float* Y = (const float*)d_in[1];
  float* out = (float*)d_out;
  char* ws = (char*)d_ws;
  // ws layout (bytes): dist 32MB | k 32MB | cx 64KB | cy 64KB | u 128KB | v 128KB | dmax 512B | crit 64B
  float* dist  = (float*)(ws);
  float* kmat  = (float*)(ws + 33554432);
  float* cx    = (float*)(ws + 67108864);
  float* cy    = (float*)(ws + 67174400);
  float* u_g   = (float*)(ws + 67239936);
  float* v_g   = (float*)(ws + 67371008);
  int*   dmax  = (int*)  (ws + 67502080);
  float* crit  = (float*)(ws + 67502592);

  hipLaunchKernelGGL(prep_kernel, dim3(128), dim3(256), 0, stream, X, Y, cx, cy, dmax, crit, out);
  hipLaunchKernelGGL(dist_kernel, dim3(128, 4, 4), dim3(256), 0, stream, X, Y, cx, cy, dist, dmax);
  hipLaunchKernelGGL(kbuild_kernel, dim3(32768), dim3(256), 0, stream, dist, dmax, kmat);

  void* args[] = { (void*)&kmat, (void*)&u_g, (void*)&v_g, (void*)&crit };
  hipLaunchCooperativeKernel((void*)sinkhorn_kernel, dim3(128), dim3(1024), args, 0, stream);

  hipLaunchKernelGGL(out_kernel, dim3(128, 16), dim3(256), 0, stream, kmat, dist, dmax, u_g, v_g, out);
}

// Round 6
// 1760.787 us; speedup vs baseline: 2.8600x; 1.1550x over previous
//
#include <hip/hip_runtime.h>
#include <hip/hip_cooperative_groups.h>
#include <math.h>

namespace cg = cooperative_groups;

#define B_N 128      // batch
#define NN 256       // n == m
#define DD 128       // feature dim
#define MAX_ITER 200
#define TOL 0.005f
#define BVAL (1.0f/256.0f)

__device__ __forceinline__ float wave_reduce_sum(float v) {
  #pragma unroll
  for (int off = 32; off >= 1; off >>= 1) v += __shfl_xor(v, off);
  return v;
}

// ---------------- K1: per-(b,d) normalization constant c = mean/sqrt(var+1e-4),
// plus zero-init of crit slots, dmax, and the dis accumulators in d_out. ----------------
__global__ __launch_bounds__(256) void prep_kernel(
    const float* __restrict__ X, const float* __restrict__ Y,
    float* __restrict__ cx, float* __restrict__ cy,
    int* __restrict__ dmax_i, float* __restrict__ crit_slots,
    float* __restrict__ out) {
  int gid = blockIdx.x * 256 + threadIdx.x;          // 0..32767
  if (gid < 16) crit_slots[gid] = 0.0f;
  if (gid < B_N) { dmax_i[gid] = (int)0xFF800000; out[gid] = 0.0f; }  // -inf bits
  const float* src = (gid < 16384) ? X : Y;
  float* dst       = (gid < 16384) ? cx : cy;
  int g = gid & 16383;
  int b = g >> 7, d = g & 127;
  const float* p = src + ((size_t)b << 15) + d;      // b*256*128 + d
  float s = 0.f, ss = 0.f;
  #pragma unroll 8
  for (int i = 0; i < NN; i++) { float x = p[(size_t)i * DD]; s += x; ss = fmaf(x, x, ss); }
  float mean = s * (1.0f/256.0f);
  float var  = (ss - 256.0f * mean * mean) * (1.0f/255.0f);   // ddof=1
  dst[g] = mean / sqrtf(var + 1e-4f);
}

// ---------------- K2: dist[b][i][j] = sum_d (Xn - Yn)^2, tiled 64x64, + per-batch max ----------------
__global__ __launch_bounds__(256) void dist_kernel(
    const float* __restrict__ X, const float* __restrict__ Y,
    const float* __restrict__ cx, const float* __restrict__ cy,
    float* __restrict__ dist, int* __restrict__ dmax_i) {
  int b  = blockIdx.x;
  int i0 = blockIdx.y * 64, j0 = blockIdx.z * 64;
  __shared__ float xs[64][65], ys[64][65];
  __shared__ int bm;
  const float* Xb  = X + (size_t)b * (NN*DD);
  const float* Yb  = Y + (size_t)b * (NN*DD);
  const float* cxb = cx + b * DD;
  const float* cyb = cy + b * DD;
  if (threadIdx.x == 0) bm = (int)0xFF800000;
  float acc[4][4] = {};
  for (int dblk = 0; dblk < DD; dblk += 64) {
    for (int t = threadIdx.x; t < 1024; t += 256) {   // 64 rows x 16 float4
      int r = t >> 4, q = t & 15;
      float4 xv = ((const float4*)(Xb + (size_t)(i0 + r) * DD + dblk))[q];
      float4 cv = ((const float4*)(cxb + dblk))[q];
      xs[r][4*q+0] = xv.x - cv.x; xs[r][4*q+1] = xv.y - cv.y;
      xs[r][4*q+2] = xv.z - cv.z; xs[r][4*q+3] = xv.w - cv.w;
      float4 yv = ((const float4*)(Yb + (size_t)(j0 + r) * DD + dblk))[q];
      float4 dv = ((const float4*)(cyb + dblk))[q];
      ys[r][4*q+0] = yv.x - dv.x; ys[r][4*q+1] = yv.y - dv.y;
      ys[r][4*q+2] = yv.z - dv.z; ys[r][4*q+3] = yv.w - dv.w;
    }
    __syncthreads();
    int ti = threadIdx.x >> 4, tj = threadIdx.x & 15;
    #pragma unroll 4
    for (int d = 0; d < 64; d++) {
      float xr[4], yc[4];
      #pragma unroll
      for (int r = 0; r < 4; r++) xr[r] = xs[ti*4+r][d];
      #pragma unroll
      for (int c = 0; c < 4; c++) yc[c] = ys[tj*4+c][d];
      #pragma unroll
      for (int r = 0; r < 4; r++)
        #pragma unroll
        for (int c = 0; c < 4; c++) { float df = xr[r] - yc[c]; acc[r][c] = fmaf(df, df, acc[r][c]); }
    }
    __syncthreads();
  }
  int ti = threadIdx.x >> 4, tj = threadIdx.x & 15;
  float mx = -INFINITY;
  #pragma unroll
  for (int r = 0; r < 4; r++) {
    float4 o = make_float4(acc[r][0], acc[r][1], acc[r][2], acc[r][3]);
    ((float4*)(dist + ((size_t)b*NN + i0 + ti*4 + r) * NN + j0))[tj] = o;
    mx = fmaxf(mx, fmaxf(fmaxf(o.x, o.y), fmaxf(o.z, o.w)));
  }
  atomicMax(&bm, __float_as_int(mx));   // dist >= 0; max is large positive
  __syncthreads();
  if (threadIdx.x == 0) atomicMax(dmax_i + b, bm);
}

// ---------------- K3: k = p * exp((s - dist/dmax)*100), elementwise ----------------
__global__ __launch_bounds__(256) void kbuild_kernel(
    const float* __restrict__ dist, const int* __restrict__ dmax_i, float* __restrict__ kmat) {
  size_t id = (size_t)blockIdx.x * 256 + threadIdx.x;   // over 128*256*256
  int b = (int)(id >> 16);
  int rem = (int)(id & 65535);
  int i = rem >> 8, j = rem & 255;
  float inv = 1.0f / __int_as_float(dmax_i[b]);
  float d  = dist[id] * inv;
  float df = (float)(i - j);
  float p  = expf(df * df * (-1.0f/400.0f)) * 0.03989422804014327f; // 1/(10*sqrt(2*pi))
  float tt = df * (1.0f/256.0f);
  float s  = 0.1f / (tt * tt + 1.0f);
  kmat[id] = p * expf((s - d) * 100.0f);
}

// ---------------- K4: cooperative Sinkhorn, K register-resident ----------------
// Layout: 16 waves; wave w owns rows [16w,16w+16). lane bits:
// lc = lane&15 (column group, 16 cols), lr = lane>>4 (row group, 4 rows).
// Lane register tile: Kreg[r][q] = K[16w+4lr+r][16lc+4q .. +4)  (4x16 floats).

// Column-partials in two halves of 8 to cap live accumulators at 8 (peak
// live ~= Kreg 64 + ur 4 + q 8 + addr ~= 80 < 128-VGPR budget).
__device__ __forceinline__ void mvT_accum(const float4 (&K)[4][4],
                                          const float* __restrict__ usrc,
                                          int row0, int w, int lc, int lr,
                                          float pt[][NN]) {
  float4 uv = *(const float4*)(usrc + row0);
  float ur[4] = {uv.x, uv.y, uv.z, uv.w};
  float4* dst = (float4*)&pt[w][lc * 16];
  #pragma unroll
  for (int h = 0; h < 2; h++) {           // half h covers c4 = 2h, 2h+1
    float q[8];
    #pragma unroll
    for (int c = 0; c < 8; c++) q[c] = 0.f;
    #pragma unroll
    for (int c4 = 0; c4 < 2; c4++) {
      #pragma unroll
      for (int r = 0; r < 4; r++) {
        q[4*c4+0] = fmaf(K[r][2*h+c4].x, ur[r], q[4*c4+0]);
        q[4*c4+1] = fmaf(K[r][2*h+c4].y, ur[r], q[4*c4+1]);
        q[4*c4+2] = fmaf(K[r][2*h+c4].z, ur[r], q[4*c4+2]);
        q[4*c4+3] = fmaf(K[r][2*h+c4].w, ur[r], q[4*c4+3]);
      }
    }
    #pragma unroll
    for (int c = 0; c < 8; c++) {
      q[c] += __shfl_xor(q[c], 16);
      q[c] += __shfl_xor(q[c], 32);
    }
    if (lr == 0) {
      dst[2*h+0] = make_float4(q[0], q[1], q[2], q[3]);
      dst[2*h+1] = make_float4(q[4], q[5], q[6], q[7]);
    }
  }
}

__device__ __forceinline__ void mvN_run(const float4 (&K)[4][4],
                                        const float* __restrict__ wsrc,
                                        int col0, int row0, int lc,
                                        float* __restrict__ udst) {
  // p[r] = sum over this lane's 16 cols of K[r][c]*w[col0+c]; reduce over lc; u = 1/(256*p).
  const float4* wv4 = (const float4*)(wsrc + col0);
  float4 w0 = wv4[0], w1 = wv4[1], w2 = wv4[2], w3 = wv4[3];
  float p[4];
  #pragma unroll
  for (int r = 0; r < 4; r++) {
    float a = K[r][0].x * w0.x;
    a = fmaf(K[r][0].y, w0.y, a); a = fmaf(K[r][0].z, w0.z, a); a = fmaf(K[r][0].w, w0.w, a);
    float bq = K[r][1].x * w1.x;
    bq = fmaf(K[r][1].y, w1.y, bq); bq = fmaf(K[r][1].z, w1.z, bq); bq = fmaf(K[r][1].w, w1.w, bq);
    a = fmaf(K[r][2].x, w2.x, a);
    a = fmaf(K[r][2].y, w2.y, a); a = fmaf(K[r][2].z, w2.z, a); a = fmaf(K[r][2].w, w2.w, a);
    bq = fmaf(K[r][3].x, w3.x, bq);
    bq = fmaf(K[r][3].y, w3.y, bq); bq = fmaf(K[r][3].z, w3.z, bq); bq = fmaf(K[r][3].w, w3.w, bq);
    p[r] = a + bq;
  }
  #pragma unroll
  for (int r = 0; r < 4; r++) {
    p[r] += __shfl_xor(p[r], 1);
    p[r] += __shfl_xor(p[r], 2);
    p[r] += __shfl_xor(p[r], 4);
    p[r] += __shfl_xor(p[r], 8);
  }
  if (lc == 0) {
    *(float4*)(udst + row0) = make_float4(1.0f/(256.0f*p[0]), 1.0f/(256.0f*p[1]),
                                          1.0f/(256.0f*p[2]), 1.0f/(256.0f*p[3]));
  }
}

// tree-order column sum over the 16 wave-partials (stride-1024B reads: 2-way bank alias = free)
__device__ __forceinline__ float colsum16(const float pt[][NN], int j) {
  float a[16];
  #pragma unroll
  for (int w = 0; w < 16; w++) a[w] = pt[w][j];
  float s0 = (a[0]+a[1]) + (a[2]+a[3]);
  float s1 = (a[4]+a[5]) + (a[6]+a[7]);
  float s2 = (a[8]+a[9]) + (a[10]+a[11]);
  float s3 = (a[12]+a[13]) + (a[14]+a[15]);
  return (s0+s1) + (s2+s3);
}

// amdgpu_waves_per_eu(4,4): min=max=4 waves/EU -> 512/4 = 128-VGPR budget; stops the
// allocator from shrinking to 64 VGPRs and spilling Kreg (R3: VGPR_Count=64, WRITE 27MB).
__global__ void __launch_bounds__(1024)
__attribute__((amdgpu_waves_per_eu(4, 4)))
sinkhorn_kernel(
    const float* __restrict__ kmat, float* __restrict__ u_g,
    float* __restrict__ v_g, float* __restrict__ crit_slots) {
  cg::grid_group grid = cg::this_grid();
  const int tid = threadIdx.x;
  const int w = tid >> 6, lane = tid & 63;
  const int lc = lane & 15, lr = lane >> 4;
  const int b = blockIdx.x;
  const int row0 = 16*w + 4*lr;
  const int col0 = 16*lc;
  const float* Kb = kmat + (size_t)b * (NN*NN);
  __shared__ __align__(16) float us[NN], wsh[NN];
  __shared__ __align__(16) float pt[16][NN];
  __shared__ float red[20];

  float4 Kreg[4][4];
  #pragma unroll
  for (int r = 0; r < 4; r++) {
    const float4* src = (const float4*)(Kb + (size_t)(row0 + r) * NN + col0);
    #pragma unroll
    for (int q = 0; q < 4; q++) Kreg[r][q] = src[q];
  }
  if (tid < NN) us[tid] = BVAL;     // u0 = 1/n
  __syncthreads();

  int compt = 0, check_idx = 0;
  bool done = false;
  while (!done && compt < MAX_ITER) {
    // ---- u1 = 1/(n * K @ (b / (K^T @ u))) ----
    mvT_accum(Kreg, us, row0, w, lc, lr, pt);
    __syncthreads();
    if (tid < NN) wsh[tid] = BVAL / colsum16(pt, tid);
    __syncthreads();
    mvN_run(Kreg, wsh, col0, row0, lc, us);
    __syncthreads();
    int c1 = compt + 1;
    bool pred = ((c1 % 20) == 1) || (c1 == MAX_ITER);
    if (!pred) { compt = c1; continue; }
    // ---- convergence branch: v2 = b/(K^T u1) ----
    mvT_accum(Kreg, us, row0, w, lc, lr, pt);
    __syncthreads();
    if (tid < NN) wsh[tid] = BVAL / colsum16(pt, tid);   // v2
    __syncthreads();
    // ---- u2 = 1/(n K v2) ----
    mvN_run(Kreg, wsh, col0, row0, lc, us);
    __syncthreads();
    // ---- crit = sum |v2 * (K^T u2) - b| ----
    mvT_accum(Kreg, us, row0, w, lc, lr, pt);
    __syncthreads();
    float cp = 0.f;
    if (tid < NN) {
      float tT3 = colsum16(pt, tid);
      cp = fabsf(wsh[tid] * tT3 - BVAL);
    }
    cp = wave_reduce_sum(cp);
    if (lane == 0) red[w] = cp;
    __syncthreads();
    if (tid == 0) atomicAdd(&crit_slots[check_idx], red[0]+red[1]+red[2]+red[3]);
    grid.sync();
    if (tid == 0)
      red[16] = __hip_atomic_load(&crit_slots[check_idx], __ATOMIC_RELAXED, __HIP_MEMORY_SCOPE_AGENT);
    __syncthreads();
    float crit = red[16];
    check_idx++;
    bool conv = (crit < TOL) || isnan(crit);
    if (conv) { done = true; compt = c1; }
    else      { compt = c1 + 1; }
  }
  if (tid < NN) {
    u_g[b*NN + tid] = us[tid];
    v_g[b*NN + tid] = wsh[tid];     // v only ever set at checks; loop always exits on a check
  }
}

// ---------------- K5: dis[b] = sum_ij u*k*(dist/dmax)*v ; t = v^T * (u*k) ----------------
__global__ __launch_bounds__(256) void out_kernel(
    const float* __restrict__ kmat, const float* __restrict__ dist,
    const int* __restrict__ dmax_i, const float* __restrict__ u_g,
    const float* __restrict__ v_g, float* __restrict__ out) {
  int b = blockIdx.x;
  int tid = threadIdx.x, lane = tid & 63, wave = tid >> 6;
  __shared__ float vs[NN];
  __shared__ float usr[16];
  __shared__ float red[4];
  vs[tid] = v_g[b * NN + tid];
  if (tid < 16) usr[tid] = u_g[b * NN + blockIdx.y * 16 + tid];
  __syncthreads();
  float inv = 1.0f / __int_as_float(dmax_i[b]);
  float vj = vs[tid];
  const float* kb = kmat + (size_t)b * (NN*NN);
  const float* db = dist + (size_t)b * (NN*NN);
  float* tout = out + B_N + (size_t)b * (NN*NN);
  float dpart = 0.f;
  #pragma unroll 4
  for (int r = 0; r < 16; r++) {
    int i = blockIdx.y * 16 + r;
    float kv = kb[i * NN + tid];
    float ui = usr[r];
    float tv = (ui * kv) * vj;                 // v^T * (u*k)
    tout[i * NN + tid] = tv;
    dpart = fmaf(tv, db[i * NN + tid] * inv, dpart);   // u*k*d*v
  }
  dpart = wave_reduce_sum(dpart);
  if (lane == 0) red[wave] = dpart;
  __syncthreads();
  if (tid == 0) atomicAdd(out + b, red[0] + red[1] + red[2] + red[3]);
}

// ---------------- launch ----------------
extern "C" void kernel_launch(void* const* d_in, const int* in_sizes, int n_in,
                              void* d_out, int out_size, void* d_ws, size_t ws_size,
                              hipStream_t stream) {
  const float* X = (const float*)d_in[0];
  const float* Y = (const float*)d_in[1];
  float* out = (float*)d_out;
  char* ws = (char*)d_ws;
  // ws layout (bytes): dist 32MB | k 32MB | cx 64KB | cy 64KB | u 128KB | v 128KB | dmax 512B | crit 64B
  float* dist  = (float*)(ws);
  float* kmat  = (float*)(ws + 33554432);
  float* cx    = (float*)(ws + 67108864);
  float* cy    = (float*)(ws + 67174400);
  float* u_g   = (float*)(ws + 67239936);
  float* v_g   = (float*)(ws + 67371008);
  int*   dmax  = (int*)  (ws + 67502080);
  float* crit  = (float*)(ws + 67502592);

  hipLaunchKernelGGL(prep_kernel, dim3(128), dim3(256), 0, stream, X, Y, cx, cy, dmax, crit, out);
  hipLaunchKernelGGL(dist_kernel, dim3(128, 4, 4), dim3(256), 0, stream, X, Y, cx, cy, dist, dmax);
  hipLaunchKernelGGL(kbuild_kernel, dim3(32768), dim3(256), 0, stream, dist, dmax, kmat);

  void* args[] = { (void*)&kmat, (void*)&u_g, (void*)&v_g, (void*)&crit };
  hipLaunchCooperativeKernel((void*)sinkhorn_kernel, dim3(128), dim3(1024), args, 0, stream);

  hipLaunchKernelGGL(out_kernel, dim3(128, 16), dim3(256), 0, stream, kmat, dist, dmax, u_g, v_g, out);
}

// Round 9
// 1191.311 us; speedup vs baseline: 4.2271x; 1.4780x over previous
//
#include <hip/hip_runtime.h>
#include <hip/hip_cooperative_groups.h>
#include <math.h>

namespace cg = cooperative_groups;

#define B_N 128      // batch
#define NN 256       // n == m
#define DD 128       // feature dim
#define MAX_ITER 200
#define TOL 0.005f
#define BVAL (1.0f/256.0f)

__device__ __forceinline__ float wave_reduce_sum(float v) {
  #pragma unroll
  for (int off = 32; off >= 1; off >>= 1) v += __shfl_xor(v, off);
  return v;
}

// ---------------- K1: per-(b,d) normalization constant c = mean/sqrt(var+1e-4),
// plus zero-init of crit slots, dmax, and the dis accumulators in d_out. ----------------
__global__ __launch_bounds__(256) void prep_kernel(
    const float* __restrict__ X, const float* __restrict__ Y,
    float* __restrict__ cx, float* __restrict__ cy,
    int* __restrict__ dmax_i, float* __restrict__ crit_slots,
    float* __restrict__ out) {
  int gid = blockIdx.x * 256 + threadIdx.x;          // 0..32767
  if (gid < 16) crit_slots[gid] = 0.0f;
  if (gid < B_N) { dmax_i[gid] = (int)0xFF800000; out[gid] = 0.0f; }  // -inf bits
  const float* src = (gid < 16384) ? X : Y;
  float* dst       = (gid < 16384) ? cx : cy;
  int g = gid & 16383;
  int b = g >> 7, d = g & 127;
  const float* p = src + ((size_t)b << 15) + d;      // b*256*128 + d
  float s = 0.f, ss = 0.f;
  #pragma unroll 8
  for (int i = 0; i < NN; i++) { float x = p[(size_t)i * DD]; s += x; ss = fmaf(x, x, ss); }
  float mean = s * (1.0f/256.0f);
  float var  = (ss - 256.0f * mean * mean) * (1.0f/255.0f);   // ddof=1
  dst[g] = mean / sqrtf(var + 1e-4f);
}

// ---------------- K2: dist[b][i][j] = sum_d (Xn - Yn)^2, tiled 64x64, + per-batch max ----------------
__global__ __launch_bounds__(256) void dist_kernel(
    const float* __restrict__ X, const float* __restrict__ Y,
    const float* __restrict__ cx, const float* __restrict__ cy,
    float* __restrict__ dist, int* __restrict__ dmax_i) {
  int b  = blockIdx.x;
  int i0 = blockIdx.y * 64, j0 = blockIdx.z * 64;
  __shared__ float xs[64][65], ys[64][65];
  __shared__ int bm;
  const float* Xb  = X + (size_t)b * (NN*DD);
  const float* Yb  = Y + (size_t)b * (NN*DD);
  const float* cxb = cx + b * DD;
  const float* cyb = cy + b * DD;
  if (threadIdx.x == 0) bm = (int)0xFF800000;
  float acc[4][4] = {};
  for (int dblk = 0; dblk < DD; dblk += 64) {
    for (int t = threadIdx.x; t < 1024; t += 256) {   // 64 rows x 16 float4
      int r = t >> 4, q = t & 15;
      float4 xv = ((const float4*)(Xb + (size_t)(i0 + r) * DD + dblk))[q];
      float4 cv = ((const float4*)(cxb + dblk))[q];
      xs[r][4*q+0] = xv.x - cv.x; xs[r][4*q+1] = xv.y - cv.y;
      xs[r][4*q+2] = xv.z - cv.z; xs[r][4*q+3] = xv.w - cv.w;
      float4 yv = ((const float4*)(Yb + (size_t)(j0 + r) * DD + dblk))[q];
      float4 dv = ((const float4*)(cyb + dblk))[q];
      ys[r][4*q+0] = yv.x - dv.x; ys[r][4*q+1] = yv.y - dv.y;
      ys[r][4*q+2] = yv.z - dv.z; ys[r][4*q+3] = yv.w - dv.w;
    }
    __syncthreads();
    int ti = threadIdx.x >> 4, tj = threadIdx.x & 15;
    #pragma unroll 4
    for (int d = 0; d < 64; d++) {
      float xr[4], yc[4];
      #pragma unroll
      for (int r = 0; r < 4; r++) xr[r] = xs[ti*4+r][d];
      #pragma unroll
      for (int c = 0; c < 4; c++) yc[c] = ys[tj*4+c][d];
      #pragma unroll
      for (int r = 0; r < 4; r++)
        #pragma unroll
        for (int c = 0; c < 4; c++) { float df = xr[r] - yc[c]; acc[r][c] = fmaf(df, df, acc[r][c]); }
    }
    __syncthreads();
  }
  int ti = threadIdx.x >> 4, tj = threadIdx.x & 15;
  float mx = -INFINITY;
  #pragma unroll
  for (int r = 0; r < 4; r++) {
    float4 o = make_float4(acc[r][0], acc[r][1], acc[r][2], acc[r][3]);
    ((float4*)(dist + ((size_t)b*NN + i0 + ti*4 + r) * NN + j0))[tj] = o;
    mx = fmaxf(mx, fmaxf(fmaxf(o.x, o.y), fmaxf(o.z, o.w)));
  }
  atomicMax(&bm, __float_as_int(mx));   // dist >= 0; max is large positive
  __syncthreads();
  if (threadIdx.x == 0) atomicMax(dmax_i + b, bm);
}

// ---------------- K3: k = p * exp((s - dist/dmax)*100), elementwise ----------------
__global__ __launch_bounds__(256) void kbuild_kernel(
    const float* __restrict__ dist, const int* __restrict__ dmax_i, float* __restrict__ kmat) {
  size_t id = (size_t)blockIdx.x * 256 + threadIdx.x;   // over 128*256*256
  int b = (int)(id >> 16);
  int rem = (int)(id & 65535);
  int i = rem >> 8, j = rem & 255;
  float inv = 1.0f / __int_as_float(dmax_i[b]);
  float d  = dist[id] * inv;
  float df = (float)(i - j);
  float p  = expf(df * df * (-1.0f/400.0f)) * 0.03989422804014327f; // 1/(10*sqrt(2*pi))
  float tt = df * (1.0f/256.0f);
  float s  = 0.1f / (tt * tt + 1.0f);
  kmat[id] = p * expf((s - d) * 100.0f);
}

// ---------------- K4: cooperative Sinkhorn, hybrid register/LDS K ----------------
// 16 waves; wave w owns rows [16w,16w+16). lane bits: lc=lane&15 (16-col group),
// lr=lane>>4 (4-row group). Lane's 4 rows: 16w+4lr+rr, rr=0..3.
//   rr=0,1 -> registers Kreg[2][4] (32 VGPR)
//   rr=2,3 -> LDS, packed slot layout so ds_read_b128 hits the 8-cycle minimum:
//   slot(w,lr,rh,q,lc) = (((w*4+lr)*2+rh)*4+q)*16+lc   (float4 units; 8192 total = 128KB)
__device__ __forceinline__ int klslot(int w, int lr, int rh, int q, int lc) {
  return ((((w << 2) + lr) * 2 + rh) * 4 + q) * 16 + lc;
}

__device__ __forceinline__ void mvT_accum(const float4 (&K)[2][4],
                                          const float4* __restrict__ kl,
                                          const float* __restrict__ usrc,
                                          int row0, int w, int lc, int lr,
                                          float pt[][NN]) {
  // q[c] = sum_r K[r][c]*u[row0+r] in r order 0,1,2,3 (rows 2,3 from LDS); reduce over lr.
  float4 uv = *(const float4*)(usrc + row0);
  float u0 = uv.x, u1 = uv.y, u2 = uv.z, u3 = uv.w;
  float4* dst = (float4*)&pt[w][lc * 16];
  #pragma unroll
  for (int h = 0; h < 2; h++) {            // half h covers columns c4 = 2h, 2h+1
    float q[8];
    #pragma unroll
    for (int c = 0; c < 8; c++) q[c] = 0.f;
    #pragma unroll
    for (int c4 = 0; c4 < 2; c4++) {
      int cc = 2*h + c4;
      float4 k0 = K[0][cc], k1 = K[1][cc];
      float4 l2 = kl[klslot(w, lr, 0, cc, lc)];
      float4 l3 = kl[klslot(w, lr, 1, cc, lc)];
      q[4*c4+0] = fmaf(l3.x, u3, fmaf(l2.x, u2, fmaf(k1.x, u1, fmaf(k0.x, u0, q[4*c4+0]))));
      q[4*c4+1] = fmaf(l3.y, u3, fmaf(l2.y, u2, fmaf(k1.y, u1, fmaf(k0.y, u0, q[4*c4+1]))));
      q[4*c4+2] = fmaf(l3.z, u3, fmaf(l2.z, u2, fmaf(k1.z, u1, fmaf(k0.z, u0, q[4*c4+2]))));
      q[4*c4+3] = fmaf(l3.w, u3, fmaf(l2.w, u2, fmaf(k1.w, u1, fmaf(k0.w, u0, q[4*c4+3]))));
    }
    #pragma unroll
    for (int c = 0; c < 8; c++) {
      q[c] += __shfl_xor(q[c], 16);
      q[c] += __shfl_xor(q[c], 32);
    }
    if (lr == 0) {
      dst[2*h+0] = make_float4(q[0], q[1], q[2], q[3]);
      dst[2*h+1] = make_float4(q[4], q[5], q[6], q[7]);
    }
  }
}

__device__ __forceinline__ void mvN_run(const float4 (&K)[2][4],
                                        const float4* __restrict__ kl,
                                        const float* __restrict__ wsrc,
                                        int col0, int row0, int w, int lc, int lr,
                                        float* __restrict__ udst) {
  // p[r] = sum_c K[r][c]*w[col0+c] (rows 2,3 from LDS); reduce over lc; u = 1/(256*p).
  const float4* wv4 = (const float4*)(wsrc + col0);
  float4 w0 = wv4[0], w1 = wv4[1], w2 = wv4[2], w3 = wv4[3];
  float p[4];
  #pragma unroll
  for (int r = 0; r < 2; r++) {
    float a = K[r][0].x * w0.x;
    a = fmaf(K[r][0].y, w0.y, a); a = fmaf(K[r][0].z, w0.z, a); a = fmaf(K[r][0].w, w0.w, a);
    float bq = K[r][1].x * w1.x;
    bq = fmaf(K[r][1].y, w1.y, bq); bq = fmaf(K[r][1].z, w1.z, bq); bq = fmaf(K[r][1].w, w1.w, bq);
    a = fmaf(K[r][2].x, w2.x, a);
    a = fmaf(K[r][2].y, w2.y, a); a = fmaf(K[r][2].z, w2.z, a); a = fmaf(K[r][2].w, w2.w, a);
    bq = fmaf(K[r][3].x, w3.x, bq);
    bq = fmaf(K[r][3].y, w3.y, bq); bq = fmaf(K[r][3].z, w3.z, bq); bq = fmaf(K[r][3].w, w3.w, bq);
    p[r] = a + bq;
  }
  #pragma unroll
  for (int rh = 0; rh < 2; rh++) {
    float4 L0 = kl[klslot(w, lr, rh, 0, lc)];
    float4 L1 = kl[klslot(w, lr, rh, 1, lc)];
    float4 L2 = kl[klslot(w, lr, rh, 2, lc)];
    float4 L3 = kl[klslot(w, lr, rh, 3, lc)];
    float a = L0.x * w0.x;
    a = fmaf(L0.y, w0.y, a); a = fmaf(L0.z, w0.z, a); a = fmaf(L0.w, w0.w, a);
    float bq = L1.x * w1.x;
    bq = fmaf(L1.y, w1.y, bq); bq = fmaf(L1.z, w1.z, bq); bq = fmaf(L1.w, w1.w, bq);
    a = fmaf(L2.x, w2.x, a);
    a = fmaf(L2.y, w2.y, a); a = fmaf(L2.z, w2.z, a); a = fmaf(L2.w, w2.w, a);
    bq = fmaf(L3.x, w3.x, bq);
    bq = fmaf(L3.y, w3.y, bq); bq = fmaf(L3.z, w3.z, bq); bq = fmaf(L3.w, w3.w, bq);
    p[2+rh] = a + bq;
  }
  #pragma unroll
  for (int r = 0; r < 4; r++) {
    p[r] += __shfl_xor(p[r], 1);
    p[r] += __shfl_xor(p[r], 2);
    p[r] += __shfl_xor(p[r], 4);
    p[r] += __shfl_xor(p[r], 8);
  }
  if (lc == 0) {
    *(float4*)(udst + row0) = make_float4(1.0f/(256.0f*p[0]), 1.0f/(256.0f*p[1]),
                                          1.0f/(256.0f*p[2]), 1.0f/(256.0f*p[3]));
  }
}

// tree-order column sum over the 16 wave-partials (stride-1024B reads: conflict-free per instr)
__device__ __forceinline__ float colsum16(const float pt[][NN], int j) {
  float a[16];
  #pragma unroll
  for (int w = 0; w < 16; w++) a[w] = pt[w][j];
  float s0 = (a[0]+a[1]) + (a[2]+a[3]);
  float s1 = (a[4]+a[5]) + (a[6]+a[7]);
  float s2 = (a[8]+a[9]) + (a[10]+a[11]);
  float s3 = (a[12]+a[13]) + (a[14]+a[15]);
  return (s0+s1) + (s2+s3);
}

__attribute__((amdgpu_waves_per_eu(4, 4)))
__global__ void __launch_bounds__(1024, 4)
sinkhorn_kernel(
    const float* __restrict__ kmat, float* __restrict__ u_g,
    float* __restrict__ v_g, float* __restrict__ crit_slots) {
  cg::grid_group grid = cg::this_grid();
  const int tid = threadIdx.x;
  const int w = tid >> 6, lane = tid & 63;
  const int lc = lane & 15, lr = lane >> 4;
  const int b = blockIdx.x;
  const int row0 = 16*w + 4*lr;
  const int col0 = 16*lc;
  const float* Kb = kmat + (size_t)b * (NN*NN);
  __shared__ __align__(16) float us[NN], wsh[NN];
  __shared__ __align__(16) float pt[16][NN];
  __shared__ float red[20];
  __shared__ __align__(16) float4 kl[8192];   // 128 KB: rows rr=2,3 of each lane-group

  float4 Kreg[2][4];
  #pragma unroll
  for (int r = 0; r < 2; r++) {
    const float4* src = (const float4*)(Kb + (size_t)(row0 + r) * NN + col0);
    #pragma unroll
    for (int q = 0; q < 4; q++) Kreg[r][q] = src[q];
  }
  #pragma unroll
  for (int rh = 0; rh < 2; rh++) {
    const float4* src = (const float4*)(Kb + (size_t)(row0 + 2 + rh) * NN + col0);
    #pragma unroll
    for (int q = 0; q < 4; q++) kl[klslot(w, lr, rh, q, lc)] = src[q];
  }
  if (tid < NN) us[tid] = BVAL;     // u0 = 1/n
  __syncthreads();

  int compt = 0, check_idx = 0;
  bool done = false;
  while (!done && compt < MAX_ITER) {
    // ---- u1 = 1/(n * K @ (b / (K^T @ u))) ----
    mvT_accum(Kreg, kl, us, row0, w, lc, lr, pt);
    __syncthreads();
    if (tid < NN) wsh[tid] = BVAL / colsum16(pt, tid);
    __syncthreads();
    mvN_run(Kreg, kl, wsh, col0, row0, w, lc, lr, us);
    __syncthreads();
    int c1 = compt + 1;
    bool pred = ((c1 % 20) == 1) || (c1 == MAX_ITER);
    if (!pred) { compt = c1; continue; }
    // ---- convergence branch: v2 = b/(K^T u1) ----
    mvT_accum(Kreg, kl, us, row0, w, lc, lr, pt);
    __syncthreads();
    if (tid < NN) wsh[tid] = BVAL / colsum16(pt, tid);   // v2
    __syncthreads();
    // ---- u2 = 1/(n K v2) ----
    mvN_run(Kreg, kl, wsh, col0, row0, w, lc, lr, us);
    __syncthreads();
    // ---- crit = sum |v2 * (K^T u2) - b| ----
    mvT_accum(Kreg, kl, us, row0, w, lc, lr, pt);
    __syncthreads();
    float cp = 0.f;
    if (tid < NN) {
      float tT3 = colsum16(pt, tid);
      cp = fabsf(wsh[tid] * tT3 - BVAL);
    }
    cp = wave_reduce_sum(cp);
    if (lane == 0) red[w] = cp;
    __syncthreads();
    if (tid == 0) atomicAdd(&crit_slots[check_idx], red[0]+red[1]+red[2]+red[3]);
    grid.sync();
    if (tid == 0)
      red[16] = __hip_atomic_load(&crit_slots[check_idx], __ATOMIC_RELAXED, __HIP_MEMORY_SCOPE_AGENT);
    __syncthreads();
    float crit = red[16];
    check_idx++;
    bool conv = (crit < TOL) || isnan(crit);
    if (conv) { done = true; compt = c1; }
    else      { compt = c1 + 1; }
  }
  if (tid < NN) {
    u_g[b*NN + tid] = us[tid];
    v_g[b*NN + tid] = wsh[tid];     // v only ever set at checks; loop always exits on a check
  }
}

// ---------------- K5: dis[b] = sum_ij u*k*(dist/dmax)*v ; t = v^T * (u*k) ----------------
__global__ __launch_bounds__(256) void out_kernel(
    const float* __restrict__ kmat, const float* __restrict__ dist,
    const int* __restrict__ dmax_i, const float* __restrict__ u_g,
    const float* __restrict__ v_g, float* __restrict__ out) {
  int b = blockIdx.x;
  int tid = threadIdx.x, lane = tid & 63, wave = tid >> 6;
  __shared__ float vs[NN];
  __shared__ float usr[16];
  __shared__ float red[4];
  vs[tid] = v_g[b * NN + tid];
  if (tid < 16) usr[tid] = u_g[b * NN + blockIdx.y * 16 + tid];
  __syncthreads();
  float inv = 1.0f / __int_as_float(dmax_i[b]);
  float vj = vs[tid];
  const float* kb = kmat + (size_t)b * (NN*NN);
  const float* db = dist + (size_t)b * (NN*NN);
  float* tout = out + B_N + (size_t)b * (NN*NN);
  float dpart = 0.f;
  #pragma unroll 4
  for (int r = 0; r < 16; r++) {
    int i = blockIdx.y * 16 + r;
    float kv = kb[i * NN + tid];
    float ui = usr[r];
    float tv = (ui * kv) * vj;                 // v^T * (u*k)
    tout[i * NN + tid] = tv;
    dpart = fmaf(tv, db[i * NN + tid] * inv, dpart);   // u*k*d*v
  }
  dpart = wave_reduce_sum(dpart);
  if (lane == 0) red[wave] = dpart;
  __syncthreads();
  if (tid == 0) atomicAdd(out + b, red[0] + red[1] + red[2] + red[3]);
}

// ---------------- launch ----------------
extern "C" void kernel_launch(void* const* d_in, const int* in_sizes, int n_in,
                              void* d_out, int out_size, void* d_ws, size_t ws_size,
                              hipStream_t stream) {
  const float* X = (const float*)d_in[0];
  const float* Y = (const float*)d_in[1];
  float* out = (float*)d_out;
  char* ws = (char*)d_ws;
  // ws layout (bytes): dist 32MB | k 32MB | cx 64KB | cy 64KB | u 128KB | v 128KB | dmax 512B | crit 64B
  float* dist  = (float*)(ws);
  float* kmat  = (float*)(ws + 33554432);
  float* cx    = (float*)(ws + 67108864);
  float* cy    = (float*)(ws + 67174400);
  float* u_g   = (float*)(ws + 67239936);
  float* v_g   = (float*)(ws + 67371008);
  int*   dmax  = (int*)  (ws + 67502080);
  float* crit  = (float*)(ws + 67502592);

  hipLaunchKernelGGL(prep_kernel, dim3(128), dim3(256), 0, stream, X, Y, cx, cy, dmax, crit, out);
  hipLaunchKernelGGL(dist_kernel, dim3(128, 4, 4), dim3(256), 0, stream, X, Y, cx, cy, dist, dmax);
  hipLaunchKernelGGL(kbuild_kernel, dim3(32768), dim3(256), 0, stream, dist, dmax, kmat);

  void* args[] = { (void*)&kmat, (void*)&u_g, (void*)&v_g, (void*)&crit };
  hipLaunchCooperativeKernel((void*)sinkhorn_kernel, dim3(128), dim3(1024), args, 0, stream);

  hipLaunchKernelGGL(out_kernel, dim3(128, 16), dim3(256), 0, stream, kmat, dist, dmax, u_g, v_g, out);
}